// Round 1
// baseline (294.660 us; speedup 1.0000x reference)
//
#include <hip/hip_runtime.h>

// Topo_Attention: out[b,c,t] = softmax_c( sum_l w[l]*tanh(sum_m v[l,m]*h_c[b,t,m]) )
// B=32, T=4096, M=256, L=128.  bf16 MFMA GEMM; memory(latency)-bound.
// R5: drop A LDS-staging entirely. A has zero cross-lane reuse: each lane's MFMA
//     A-fragment is 32 contiguous bytes of one global row -> load straight from
//     global into registers (2x float4/step, depth-2 register prefetch), convert
//     fp32->bf16 in-reg. LDS now V-only (64KB) -> 2 WG/CU = 16 waves/CU (was 8,
//     21.5% occupancy, latency-bound at MfmaUtil 6%/VALUBusy 15%). No vmcnt FIFO
//     coupling, no barriers in main loop. Numerics bit-identical to R1-R4.

typedef unsigned short u16;
typedef unsigned int   u32;
typedef __bf16 bf16x8 __attribute__((ext_vector_type(8)));
typedef float  f32x4  __attribute__((ext_vector_type(4)));

union ABFrag { bf16x8 v; u16 u[8]; uint4 q4; };

__device__ __forceinline__ u16 f2bf(float f) {
  // round-to-nearest-even fp32 -> bf16 (finite inputs; no NaN path)
  u32 u = __float_as_uint(f);
  u += 0x7fffu + ((u >> 16) & 1u);
  return (u16)(u >> 16);
}

__device__ __forceinline__ float fast_tanh(float x) {
  float t = __builtin_amdgcn_exp2f(2.885390082f * x);
  return 1.0f - 2.0f * __builtin_amdgcn_rcpf(t + 1.0f);
}

#define NWG    512
#define ITERS  4
#define TOT    (ITERS * 8)
#define ROWS_PER_IT (NWG * 64)     // 32768 t-rows per iter across the device
#define SMEMSZ 65536               // V bf16 only

__global__ __launch_bounds__(512, 4) void topo_attn_kernel(
    const float* __restrict__ h1, const float* __restrict__ h2,
    const float* __restrict__ w,  const float* __restrict__ vfp,
    float* __restrict__ out) {
  extern __shared__ __align__(16) char smem[];
  u16* vlds = (u16*)smem;          // V bf16, R1 rotate layout (64KB)

  const int tid = threadIdx.x;

  { // one-time: convert V fp32 -> bf16 into LDS, rotate swizzle (chunk g -> (g+l)&31)
    const float4* src = (const float4*)vfp;
    #pragma unroll
    for (int k = 0; k < 8; ++k) {
      int gi = k * 512 + tid;            // 8-elem group index, 0..4095
      float4 f0 = src[gi * 2];
      float4 f1 = src[gi * 2 + 1];
      ABFrag t;
      t.u[0] = f2bf(f0.x); t.u[1] = f2bf(f0.y); t.u[2] = f2bf(f0.z); t.u[3] = f2bf(f0.w);
      t.u[4] = f2bf(f1.x); t.u[5] = f2bf(f1.y); t.u[6] = f2bf(f1.z); t.u[7] = f2bf(f1.w);
      int l = gi >> 5;                   // 0..127
      int g = gi & 31;                   // 0..31
      *(uint4*)&vlds[(l << 8) + (((g + l) & 31) << 3)] = t.q4;
    }
  }
  __syncthreads();                       // only barrier in the kernel

  const int lane = tid & 63;
  const int wave = tid >> 6;             // 0..7
  const int l15  = lane & 15;            // MFMA A-row / D-col lane index
  const int q    = lane >> 4;            // quad: A k = q*8+j ; D row = q*4+reg

  float wreg[8];
  #pragma unroll
  for (int lt = 0; lt < 8; ++lt) wreg[lt] = w[lt * 16 + l15];

  const int n0base = (blockIdx.x * 8 + wave) * 8;   // t-rows for it=0

  // Per-lane A source: A-row l15 (0-7 = h1 rows n0+l15, 8-15 = h2 rows n0+l15-8),
  // k-offset q*8 floats. Each lane's 32B fragment is contiguous in global memory;
  // each 128B line is fetched once and fully consumed by the 4 q-lanes of its row.
  const float* ap = (l15 < 8)
      ? h1 + (size_t)(n0base + l15) * 256
      : h2 + (size_t)(n0base + l15 - 8) * 256;
  ap += q * 8;

  // step s = it*8+ks: float offset = (s>>3)*ROWS_PER_IT*256 + (s&7)*32
  #define LDA(s, x, y) do {                                                       \
    const float* _p = ap + (size_t)((s) >> 3) * ((size_t)ROWS_PER_IT * 256)       \
                         + ((s) & 7) * 32;                                        \
    (x) = *(const float4*)_p; (y) = *(const float4*)(_p + 4); } while (0)

  float4 cfa, cfb, nfa, nfb;             // current / next (depth-2 reg pipeline)
  LDA(0, cfa, cfb);
  LDA(1, nfa, nfb);

  #pragma unroll
  for (int it = 0; it < ITERS; ++it) {
    f32x4 acc[8];
    #pragma unroll
    for (int lt = 0; lt < 8; ++lt) acc[lt] = (f32x4){0.f, 0.f, 0.f, 0.f};

    #pragma unroll
    for (int ks = 0; ks < 8; ++ks) {
      const int s = it * 8 + ks;
      float4 mfa = cfa, mfb = cfb;       // dead at tail; overwritten otherwise
      if (s + 2 < TOT) LDA(s + 2, mfa, mfb);

      ABFrag a;                          // fp32 -> bf16 in-register
      a.u[0] = f2bf(cfa.x); a.u[1] = f2bf(cfa.y); a.u[2] = f2bf(cfa.z); a.u[3] = f2bf(cfa.w);
      a.u[4] = f2bf(cfb.x); a.u[5] = f2bf(cfb.y); a.u[6] = f2bf(cfb.z); a.u[7] = f2bf(cfb.w);

      #pragma unroll
      for (int lt = 0; lt < 8; ++lt) {
        const int l = (lt << 4) + l15;
        bf16x8 bfr = *(const bf16x8*)&vlds[(l << 8) + (((4 * ks + q + l) & 31) << 3)];
        acc[lt] = __builtin_amdgcn_mfma_f32_16x16x32_bf16(a.v, bfr, acc[lt], 0, 0, 0);
      }
      cfa = nfa; cfb = nfb; nfa = mfa; nfb = mfb;
    }

    // Epilogue: s_p[r] = sum_l w[l]*tanh(temp); D: col L=16*lt+l15, row m=q*4+r.
    // Rows m=0..7 are stream-0 (h1) scores, m=8..15 stream-1 (h2), same t-rows.
    float s_p[4] = {0.f, 0.f, 0.f, 0.f};
    #pragma unroll
    for (int lt = 0; lt < 8; ++lt) {
      #pragma unroll
      for (int r = 0; r < 4; ++r)
        s_p[r] += wreg[lt] * fast_tanh(acc[lt][r]);
    }
    #pragma unroll
    for (int r = 0; r < 4; ++r) {
      #pragma unroll
      for (int off = 1; off < 16; off <<= 1)
        s_p[r] += __shfl_xor(s_p[r], off);
    }
    const int r = l15 & 3;
    float sel = (r == 0) ? s_p[0] : (r == 1) ? s_p[1] : (r == 2) ? s_p[2] : s_p[3];
    float oth = __shfl_xor(sel, 32);     // partner quad carries the other stream
    if (q < 2 && l15 < 4) {
      int n = n0base + it * ROWS_PER_IT + q * 4 + l15;
      int b = n >> 12, t = n & 4095;
      float e  = __builtin_amdgcn_exp2f(-1.442695041f * (sel - oth));
      float a0 = __builtin_amdgcn_rcpf(1.0f + e);
      out[b * 8192 + t]        = a0;
      out[b * 8192 + 4096 + t] = 1.0f - a0;
    }
  }
}

extern "C" void kernel_launch(void* const* d_in, const int* in_sizes, int n_in,
                              void* d_out, int out_size, void* d_ws, size_t ws_size,
                              hipStream_t stream) {
  const float* h1 = (const float*)d_in[0];   // (32,4096,256) fp32
  const float* h2 = (const float*)d_in[1];   // (32,4096,256) fp32
  const float* w  = (const float*)d_in[2];   // (1,128) fp32
  const float* v  = (const float*)d_in[3];   // (128,256) fp32
  float* out = (float*)d_out;                // (32,2,4096) fp32

  hipFuncSetAttribute((const void*)topo_attn_kernel,
                      hipFuncAttributeMaxDynamicSharedMemorySize, SMEMSZ);
  topo_attn_kernel<<<NWG, 512, SMEMSZ, stream>>>(h1, h2, w, v, out);
}

// Round 2
// 293.054 us; speedup vs baseline: 1.0055x; 1.0055x over previous
//
#include <hip/hip_runtime.h>

// Topo_Attention: out[b,c,t] = softmax_c( sum_l w[l]*tanh(sum_m v[l,m]*h_c[b,t,m]) )
// B=32, T=4096, M=256, L=128.  bf16 MFMA GEMM; memory(latency)-bound.
// R6: R5 (A direct global->reg, V-only 64KB LDS, 2 WG/CU = 16 waves) minus the
//     spill. R5's 19.4MB WRITE_SIZE (output is 1MB) = scratch spill: the fully
//     unrolled 32-step loop let the scheduler hoist unrolled loads, blowing the
//     128-reg launch_bounds cap. Fix: (a) sched_barrier(0) at each ks-step
//     boundary pins the pipeline depth, (b) static pf[4][2] depth-3 rolling
//     buffer (no copy temps), (c) ITERS 4->2 / NWG 512->1024 halves the
//     unrolled span. Numerics bit-identical to R1-R5.

typedef unsigned short u16;
typedef unsigned int   u32;
typedef __bf16 bf16x8 __attribute__((ext_vector_type(8)));
typedef float  f32x4  __attribute__((ext_vector_type(4)));

union ABFrag { bf16x8 v; u16 u[8]; uint4 q4; };

__device__ __forceinline__ u16 f2bf(float f) {
  // round-to-nearest-even fp32 -> bf16 (finite inputs; no NaN path)
  u32 u = __float_as_uint(f);
  u += 0x7fffu + ((u >> 16) & 1u);
  return (u16)(u >> 16);
}

__device__ __forceinline__ float fast_tanh(float x) {
  float t = __builtin_amdgcn_exp2f(2.885390082f * x);
  return 1.0f - 2.0f * __builtin_amdgcn_rcpf(t + 1.0f);
}

#define NWG    1024
#define ITERS  2
#define TOT    (ITERS * 8)          // 16 ks-steps
#define ROWS_PER_IT (NWG * 64)      // 65536 t-rows per iter across the device
#define SMEMSZ 65536                // V bf16 only

__global__ __launch_bounds__(512, 4) void topo_attn_kernel(
    const float* __restrict__ h1, const float* __restrict__ h2,
    const float* __restrict__ w,  const float* __restrict__ vfp,
    float* __restrict__ out) {
  extern __shared__ __align__(16) char smem[];
  u16* vlds = (u16*)smem;          // V bf16, R1 rotate layout (64KB)

  const int tid = threadIdx.x;

  { // one-time: convert V fp32 -> bf16 into LDS, rotate swizzle (chunk g -> (g+l)&31)
    const float4* src = (const float4*)vfp;
    #pragma unroll
    for (int k = 0; k < 8; ++k) {
      int gi = k * 512 + tid;            // 8-elem group index, 0..4095
      float4 f0 = src[gi * 2];
      float4 f1 = src[gi * 2 + 1];
      ABFrag t;
      t.u[0] = f2bf(f0.x); t.u[1] = f2bf(f0.y); t.u[2] = f2bf(f0.z); t.u[3] = f2bf(f0.w);
      t.u[4] = f2bf(f1.x); t.u[5] = f2bf(f1.y); t.u[6] = f2bf(f1.z); t.u[7] = f2bf(f1.w);
      int l = gi >> 5;                   // 0..127
      int g = gi & 31;                   // 0..31
      *(uint4*)&vlds[(l << 8) + (((g + l) & 31) << 3)] = t.q4;
    }
  }
  __syncthreads();                       // only barrier in the kernel

  const int lane = tid & 63;
  const int wave = tid >> 6;             // 0..7
  const int l15  = lane & 15;            // MFMA A-row / D-col lane index
  const int q    = lane >> 4;            // quad: A k = q*8+j ; D row = q*4+reg

  float wreg[8];
  #pragma unroll
  for (int lt = 0; lt < 8; ++lt) wreg[lt] = w[lt * 16 + l15];

  const int n0base = (blockIdx.x * 8 + wave) * 8;   // t-rows for it=0

  // Per-lane A source: A-row l15 (0-7 = h1 rows n0+l15, 8-15 = h2 rows n0+l15-8),
  // k-offset q*8 floats. Each lane's 32B fragment is contiguous in global memory;
  // each 128B line is fetched once and fully consumed by the 4 q-lanes of its row.
  const float* ap = (l15 < 8)
      ? h1 + (size_t)(n0base + l15) * 256
      : h2 + (size_t)(n0base + l15 - 8) * 256;
  ap += q * 8;

  // step s = it*8+ks: float offset = (s>>3)*ROWS_PER_IT*256 + (s&7)*32
  #define LDA(s, x, y) do {                                                       \
    const float* _p = ap + (size_t)((s) >> 3) * ((size_t)ROWS_PER_IT * 256)       \
                         + ((s) & 7) * 32;                                        \
    (x) = *(const float4*)_p; (y) = *(const float4*)(_p + 4); } while (0)

  // Depth-3 register pipeline; all pf indices compile-time (full unroll).
  float4 pf[4][2];
  LDA(0, pf[0][0], pf[0][1]);
  LDA(1, pf[1][0], pf[1][1]);
  LDA(2, pf[2][0], pf[2][1]);

  #pragma unroll
  for (int it = 0; it < ITERS; ++it) {
    f32x4 acc[8];
    #pragma unroll
    for (int lt = 0; lt < 8; ++lt) acc[lt] = (f32x4){0.f, 0.f, 0.f, 0.f};

    #pragma unroll
    for (int ks = 0; ks < 8; ++ks) {
      const int s = it * 8 + ks;
      // Pin the pipeline: nothing crosses a step boundary. Within the step the
      // scheduler is free (f2bf/MFMA/ds_read interleave). Prevents the R5
      // failure: hoisting all unrolled loads -> VGPR spill -> 19MB scratch.
      __builtin_amdgcn_sched_barrier(0);
      if (s + 3 < TOT) LDA(s + 3, pf[(s + 3) & 3][0], pf[(s + 3) & 3][1]);

      const float4 cfa = pf[s & 3][0];
      const float4 cfb = pf[s & 3][1];
      ABFrag a;                          // fp32 -> bf16 in-register
      a.u[0] = f2bf(cfa.x); a.u[1] = f2bf(cfa.y); a.u[2] = f2bf(cfa.z); a.u[3] = f2bf(cfa.w);
      a.u[4] = f2bf(cfb.x); a.u[5] = f2bf(cfb.y); a.u[6] = f2bf(cfb.z); a.u[7] = f2bf(cfb.w);

      #pragma unroll
      for (int lt = 0; lt < 8; ++lt) {
        const int l = (lt << 4) + l15;
        bf16x8 bfr = *(const bf16x8*)&vlds[(l << 8) + (((4 * ks + q + l) & 31) << 3)];
        acc[lt] = __builtin_amdgcn_mfma_f32_16x16x32_bf16(a.v, bfr, acc[lt], 0, 0, 0);
      }
    }

    // Epilogue: s_p[r] = sum_l w[l]*tanh(temp); D: col L=16*lt+l15, row m=q*4+r.
    // Rows m=0..7 are stream-0 (h1) scores, m=8..15 stream-1 (h2), same t-rows.
    float s_p[4] = {0.f, 0.f, 0.f, 0.f};
    #pragma unroll
    for (int lt = 0; lt < 8; ++lt) {
      #pragma unroll
      for (int r = 0; r < 4; ++r)
        s_p[r] += wreg[lt] * fast_tanh(acc[lt][r]);
    }
    #pragma unroll
    for (int r = 0; r < 4; ++r) {
      #pragma unroll
      for (int off = 1; off < 16; off <<= 1)
        s_p[r] += __shfl_xor(s_p[r], off);
    }
    const int r = l15 & 3;
    float sel = (r == 0) ? s_p[0] : (r == 1) ? s_p[1] : (r == 2) ? s_p[2] : s_p[3];
    float oth = __shfl_xor(sel, 32);     // partner quad carries the other stream
    if (q < 2 && l15 < 4) {
      int n = n0base + it * ROWS_PER_IT + q * 4 + l15;
      int b = n >> 12, t = n & 4095;
      float e  = __builtin_amdgcn_exp2f(-1.442695041f * (sel - oth));
      float a0 = __builtin_amdgcn_rcpf(1.0f + e);
      out[b * 8192 + t]        = a0;
      out[b * 8192 + 4096 + t] = 1.0f - a0;
    }
  }
}

extern "C" void kernel_launch(void* const* d_in, const int* in_sizes, int n_in,
                              void* d_out, int out_size, void* d_ws, size_t ws_size,
                              hipStream_t stream) {
  const float* h1 = (const float*)d_in[0];   // (32,4096,256) fp32
  const float* h2 = (const float*)d_in[1];   // (32,4096,256) fp32
  const float* w  = (const float*)d_in[2];   // (1,128) fp32
  const float* v  = (const float*)d_in[3];   // (128,256) fp32
  float* out = (float*)d_out;                // (32,2,4096) fp32

  hipFuncSetAttribute((const void*)topo_attn_kernel,
                      hipFuncAttributeMaxDynamicSharedMemorySize, SMEMSZ);
  topo_attn_kernel<<<NWG, 512, SMEMSZ, stream>>>(h1, h2, w, v, out);
}